// Round 2
// baseline (4311.702 us; speedup 1.0000x reference)
//
#include <hip/hip_runtime.h>

typedef unsigned short u16;
typedef short short8 __attribute__((ext_vector_type(8)));
typedef float f32x4 __attribute__((ext_vector_type(4)));
typedef unsigned int u32x2 __attribute__((ext_vector_type(2)));
typedef unsigned short u16x4 __attribute__((ext_vector_type(4)));

#define Bsz 32
#define Tsz 512
#define Dsz 1024
#define Usz 1024
#define Gsz 4096   // 4*U

// ---- bf16 helpers (manual RNE) ----
static __device__ __forceinline__ u16 f2bf(float f) {
    unsigned int u = __float_as_uint(f);
    unsigned int lsb = (u >> 16) & 1u;
    u += 0x7fffu + lsb;
    return (u16)(u >> 16);
}
static __device__ __forceinline__ float bf2f(u16 b) {
    return __uint_as_float(((unsigned int)b) << 16);
}

// =====================================================================
// Pack kernels: MFMA-fragment-ordered bf16 buffers.
// A-frag (16x16x32): lane L holds A[m = mt*16 + (L&15)][k = kb*32 + (L>>4)*8 + j]
// B-frag:            lane L holds B[k = kb*32 + (L>>4)*8 + j][n = nt*16 + (L&15)]
// Flat: buf[((tile*32 + kb)*64 + L)*8 + j] -> lane-contiguous 16B chunks.
// =====================================================================

__global__ __launch_bounds__(256) void pack_a(const float* __restrict__ x, u16* __restrict__ Af) {
    size_t tid = (size_t)blockIdx.x * 256 + threadIdx.x;
    int L = (int)(tid & 63);
    size_t mtkb = tid >> 6;
    int kb = (int)(mtkb & 31);
    int mt = (int)(mtkb >> 5);
    int m  = mt * 16 + (L & 15);
    int d0 = kb * 32 + (L >> 4) * 8;
    const float* src = x + (size_t)m * Dsz + d0;
    short8 v;
#pragma unroll
    for (int j = 0; j < 8; ++j) v[j] = (short)f2bf(src[j]);
    *(short8*)(Af + tid * 8) = v;
}

__global__ __launch_bounds__(256) void pack_b(const float* __restrict__ W, u16* __restrict__ Bf) {
    size_t tid = (size_t)blockIdx.x * 256 + threadIdx.x;
    int L = (int)(tid & 63);
    size_t ntkb = tid >> 6;
    int kb = (int)(ntkb & 31);
    int nt = (int)(ntkb >> 5);
    int n  = nt * 16 + (L & 15);
    int k0 = kb * 32 + (L >> 4) * 8;
    short8 v;
#pragma unroll
    for (int j = 0; j < 8; ++j) v[j] = (short)f2bf(W[(size_t)(k0 + j) * Gsz + n]);
    *(short8*)(Bf + tid * 8) = v;
}

// R -> Rp block-major gate-interleaved for the 64-block scan:
// tile t_g (0..255) covers u = (t_g>>2)*16 + (t_g&3)*4 + du, packed col c
// within tile: gate = c>>2, du = c&3.  scan block blk owns tiles blk*4..+3.
// Also zeroes the barrier flags (ws is poisoned 0xAA before every call!).
__global__ __launch_bounds__(256) void pack_r(const float* __restrict__ R, u16* __restrict__ Rp,
                                              unsigned* __restrict__ flags) {
    if (blockIdx.x == 0) flags[threadIdx.x] = 0;
    size_t tid = (size_t)blockIdx.x * 256 + threadIdx.x;
    int L = (int)(tid & 63);
    size_t tkb = tid >> 6;
    int kb   = (int)(tkb & 31);
    int tile = (int)(tkb >> 5);          // 0..255
    int c = L & 15;
    int g = (c >> 2) * 1024 + (tile >> 2) * 16 + (tile & 3) * 4 + (c & 3);
    int k0 = kb * 32 + (L >> 4) * 8;
    short8 v;
#pragma unroll
    for (int j = 0; j < 8; ++j) v[j] = (short)f2bf(R[(size_t)(k0 + j) * Gsz + g]);
    *(short8*)(Rp + tid * 8) = v;
}

// =====================================================================
// GEMM1: x_proj = X @ W; 128x128 tile, 4 waves. Epilogue writes the
// scan layout: [t][blk(64)][b(32)][ul(16)][gate(4)] so each scan thread
// reads exactly one float4/u16x4 per (t,b,ul).
// =====================================================================
__global__ __launch_bounds__(256) void gemm1(const u16* __restrict__ Af, const u16* __restrict__ Bf,
                                             float* __restrict__ xpf, u16* __restrict__ xph, int xp32) {
    __shared__ u16 smem[16 * 512];
    int bm = blockIdx.x >> 5;
    int bn = blockIdx.x & 31;
    int tid = threadIdx.x;
    int w = tid >> 6, ln = tid & 63;
    int mw = w & 1, nw = w >> 1;

    f32x4 acc[4][4];
#pragma unroll
    for (int i = 0; i < 4; ++i)
#pragma unroll
        for (int j = 0; j < 4; ++j) acc[i][j] = (f32x4){0.f, 0.f, 0.f, 0.f};

    for (int kb = 0; kb < 32; ++kb) {
        short8 tmp[4];
#pragma unroll
        for (int c2 = 0; c2 < 4; ++c2) {
            int chunk = w * 4 + c2;
            const u16* src = (chunk < 8)
                ? Af + (((size_t)(bm * 8 + chunk) * 32 + kb) * 64 + ln) * 8
                : Bf + (((size_t)(bn * 8 + (chunk - 8)) * 32 + kb) * 64 + ln) * 8;
            tmp[c2] = *(const short8*)src;
        }
#pragma unroll
        for (int c2 = 0; c2 < 4; ++c2) {
            int chunk = w * 4 + c2;
            *(short8*)(smem + chunk * 512 + ln * 8) = tmp[c2];
        }
        __syncthreads();
        short8 av[4], bv[4];
#pragma unroll
        for (int i = 0; i < 4; ++i) av[i] = *(const short8*)(smem + (mw * 4 + i) * 512 + ln * 8);
#pragma unroll
        for (int j = 0; j < 4; ++j) bv[j] = *(const short8*)(smem + (8 + nw * 4 + j) * 512 + ln * 8);
#pragma unroll
        for (int i = 0; i < 4; ++i)
#pragma unroll
            for (int j = 0; j < 4; ++j)
                acc[i][j] = __builtin_amdgcn_mfma_f32_16x16x32_bf16(av[i], bv[j], acc[i][j], 0, 0, 0);
        __syncthreads();
    }

    int quad = ln >> 4, c15 = ln & 15;
#pragma unroll
    for (int i = 0; i < 4; ++i) {
        int mt_g = bm * 8 + mw * 4 + i;
#pragma unroll
        for (int j = 0; j < 4; ++j) {
            int g = (bn * 8 + nw * 4 + j) * 16 + c15;   // original W column
            int gate = g >> 10;
            int u = g & 1023;
            int blkw = u >> 4, ulw = u & 15;
#pragma unroll
            for (int r = 0; r < 4; ++r) {
                int row = mt_g * 16 + quad * 4 + r;
                int bb = row >> 9, tt = row & 511;
                size_t o = ((size_t)tt * 64 + blkw) * 2048 + (size_t)bb * 64 + (size_t)(ulw * 4 + gate);
                if (xp32) xpf[o] = acc[i][j][r];
                else      xph[o] = f2bf(acc[i][j][r]);
            }
        }
    }
}

// =====================================================================
// Scan: 64 blocks x 512 threads (8 waves). Wave = (mt in 2, kh in 2,
// nh in 2): rows mt*16..+15, K-slice kh*512..+511, 2 n-tiles nh*2..+1.
// R slice (128KB) lives in LDS (fragment order -> contiguous b128
// reads feed MFMA; NO giant register array -> no scratch spills, which
// is what killed the previous round at VGPR_Count=104 < 128 needed).
// h-broadcast: each (mt,kh) fragment read by 2 waves -> 8MB/step LLC
// (vs 16MB in the 256-block version).
// Protocol: poll flags >= t+1 -> bypass-load h_{t-1} (16 loads) ->
// issue x_proj(t+1) prefetch -> vmcnt(1) (h done, prefetch in flight
// across MFMA/reduce/gates) -> MFMA -> kh-pair LDS reduce -> gates ->
// bypass-store h_t -> vmcnt(0)/barrier -> flag = t+2.
// =====================================================================
__global__ __launch_bounds__(512) void scan_all(const float* __restrict__ xpf,
                                                const u16* __restrict__ xph, int xp32,
                                                const u16* __restrict__ Rp,
                                                const float* __restrict__ bias,
                                                u16* __restrict__ hbf, float* __restrict__ out,
                                                unsigned* __restrict__ flags) {
    __shared__ u16 lds_r[65536];          // 128KB: this block's Rp slice (4 tiles x 32 kb)
    __shared__ f32x4 partial[4][2][64];   // 8KB: [nh*2+mt][tile][lane]
    __shared__ float proj[32 * 4 * 17];   // 8.7KB: (b*4+gate)*17 + ul

    int tid = threadIdx.x;
    int blk = blockIdx.x;
    int w = tid >> 6, ln = tid & 63, quad = ln >> 4, c15 = ln & 15;
    int mt = w & 1, kh = (w >> 1) & 1, nh = w >> 2;
    int tl0 = nh * 2, tl1 = nh * 2 + 1;
    int slot = nh * 2 + mt;
    int b_row = tid >> 4, ul = tid & 15;
    int u_g = blk * 16 + ul;

    u16* hb0 = hbf;                       // written at even t
    u16* hb1 = hbf + 32 * 1024;           // written at odd t; zeros for t=0

    // ---- stage Rp slice into LDS (fragment order preserved) ----
    const u16* rsrc = Rp + (size_t)blk * 65536;
#pragma unroll
    for (int i = 0; i < 16; ++i)
        *(short8*)(lds_r + (size_t)(i * 512 + tid) * 8) = *(const short8*)(rsrc + (size_t)(i * 512 + tid) * 8);

    float bi0 = bias[u_g], bi1 = bias[1024 + u_g], bi2 = bias[2048 + u_g], bi3 = bias[3072 + u_g];
    float cs = 0.f, ns = 0.f, ms = 0.f;
    f32x4 xraw4 = (f32x4){0.f, 0.f, 0.f, 0.f};
    u32x2 xraw2 = (u32x2){0u, 0u};

    {   // h_{-1} = 0 in hb1 (bypass store -> LLC); t=0 x_proj prefetch
        u16* hp = hb1 + b_row * Usz + u_g;
        unsigned z = 0;
        asm volatile("global_store_short %0, %1, off sc0 sc1" :: "v"(hp), "v"(z) : "memory");
        size_t o0 = (size_t)blk * 2048 + (size_t)b_row * 64 + (size_t)(ul * 4);
        if (xp32) xraw4 = *(const f32x4*)(xpf + o0);
        else      xraw2 = *(const u32x2*)(xph + o0);
    }
    asm volatile("s_waitcnt vmcnt(0)" ::: "memory");
    __builtin_amdgcn_sched_barrier(0);
    __syncthreads();
    if (tid == 0) {
        unsigned* fp = flags + blk;
        unsigned one = 1;
        asm volatile("global_store_dword %0, %1, off sc0 sc1" :: "v"(fp), "v"(one) : "memory");
    }

    // per-wave constant h-fragment bases (16 x 64B chunk imm offsets)
    const u16* aB0 = hb0 + (size_t)(mt * 16 + c15) * Usz + kh * 512 + quad * 8;
    const u16* aB1 = hb1 + (size_t)(mt * 16 + c15) * Usz + kh * 512 + quad * 8;

    for (int t = 0; t < Tsz; ++t) {
        // ---- every wave polls all 64 flags (1/lane); own flag masked ----
        {
            const unsigned* fp1 = flags + ln;
            unsigned tgt = (unsigned)(t + 1);
            unsigned fv;
            do {
                asm volatile("global_load_dword %0, %1, off sc0 sc1\n\ts_waitcnt vmcnt(0)"
                             : "=v"(fv) : "v"(fp1) : "memory");
                if (ln == blk) fv = ~0u;
            } while (__any((int)(fv < tgt)));
        }

        // consume prefetched x_proj (completed: drained by previous step's vmcnt(0))
        float xv0, xv1, xv2, xv3;
        if (xp32) { xv0 = xraw4[0]; xv1 = xraw4[1]; xv2 = xraw4[2]; xv3 = xraw4[3]; }
        else {
            xv0 = bf2f((u16)(xraw2[0] & 0xffffu)); xv1 = bf2f((u16)(xraw2[0] >> 16));
            xv2 = bf2f((u16)(xraw2[1] & 0xffffu)); xv3 = bf2f((u16)(xraw2[1] >> 16));
        }

        // ---- bypass-load this wave's h_{t-1} fragment (16 x 16B per lane) ----
        const u16* aBw = (t & 1) ? aB0 : aB1;
        short8 av[16];
#define LDH(i, OFF) asm volatile("global_load_dwordx4 %0, %1, off offset:" OFF " sc0 sc1" \
                                 : "=v"(av[i]) : "v"(aBw))
        LDH(0, "0");   LDH(1, "64");   LDH(2, "128");  LDH(3, "192");
        LDH(4, "256"); LDH(5, "320");  LDH(6, "384");  LDH(7, "448");
        LDH(8, "512"); LDH(9, "576");  LDH(10, "640"); LDH(11, "704");
        LDH(12, "768"); LDH(13, "832"); LDH(14, "896"); LDH(15, "960");
#undef LDH
        // issue next x_proj prefetch LAST -> vmcnt(1) waits only for the h loads;
        // the prefetch stays in flight under MFMA/reduce/gates, drained at step end.
        {
            int tn = (t + 1 < Tsz) ? t + 1 : t;
            size_t o = ((size_t)tn * 64 + blk) * 2048 + (size_t)b_row * 64 + (size_t)(ul * 4);
            if (xp32) {
                const float* p = xpf + o;
                asm volatile("global_load_dwordx4 %0, %1, off" : "=v"(xraw4) : "v"(p));
            } else {
                const u16* p = xph + o;
                asm volatile("global_load_dwordx2 %0, %1, off" : "=v"(xraw2) : "v"(p));
            }
        }
        asm volatile("s_waitcnt vmcnt(1)" ::: "memory");
        __builtin_amdgcn_sched_barrier(0);

        // ---- MFMA: 2 chains (one per n-tile), B from LDS b128 reads ----
        f32x4 acc0 = (f32x4){0.f, 0.f, 0.f, 0.f};
        f32x4 acc1 = (f32x4){0.f, 0.f, 0.f, 0.f};
#pragma unroll
        for (int kk = 0; kk < 16; ++kk) {
            int kb = kh * 16 + kk;
            short8 b0 = *(const short8*)(lds_r + ((size_t)(tl0 * 32 + kb) * 64 + ln) * 8);
            short8 b1 = *(const short8*)(lds_r + ((size_t)(tl1 * 32 + kb) * 64 + ln) * 8);
            acc0 = __builtin_amdgcn_mfma_f32_16x16x32_bf16(av[kk], b0, acc0, 0, 0, 0);
            acc1 = __builtin_amdgcn_mfma_f32_16x16x32_bf16(av[kk], b1, acc1, 0, 0, 0);
        }

        // ---- kh-pair reduce through LDS ----
        if (kh) { partial[slot][0][ln] = acc0; partial[slot][1][ln] = acc1; }
        __syncthreads();
        if (!kh) {
            acc0 += partial[slot][0][ln];
            acc1 += partial[slot][1][ln];
            int gate = c15 >> 2, du = c15 & 3;
#pragma unroll
            for (int r = 0; r < 4; ++r) {
                proj[((mt * 16 + quad * 4 + r) * 4 + gate) * 17 + tl0 * 4 + du] = acc0[r];
                proj[((mt * 16 + quad * 4 + r) * 4 + gate) * 17 + tl1 * 4 + du] = acc1[r];
            }
        }
        __syncthreads();

        // ---- gates: every thread owns one (b,u) ----
        float ip = proj[(b_row * 4 + 0) * 17 + ul] + xv0 + bi0;
        float fp = proj[(b_row * 4 + 1) * 17 + ul] + xv1 + bi1;
        float op = proj[(b_row * 4 + 2) * 17 + ul] + xv2 + bi2;
        float zp = proj[(b_row * 4 + 3) * 17 + ul] + xv3 + bi3;
        float sf = 1.f / (1.f + __expf(-fp));
        float lf = __logf(sf + 1e-8f);
        float mn = fmaxf(ms + lf, ip);
        float it = __expf(ip - mn);
        float ft = __expf(ms + lf - mn);
        float ot = 1.f / (1.f + __expf(-op));
        float zt = tanhf(zp);
        cs = ft * cs + it * zt;
        ns = ft * ns + it;
        ms = mn;
        float h = ot * (cs / (ns + 1e-8f));
        out[(size_t)b_row * (Tsz * Usz) + (size_t)t * Usz + u_g] = h;   // plain (flushed at kernel end)
        u16* hp = ((t & 1) ? hb1 : hb0) + b_row * Usz + u_g;
        unsigned hv = (unsigned)f2bf(h);
        asm volatile("global_store_short %0, %1, off sc0 sc1" :: "v"(hp), "v"(hv) : "memory");
        asm volatile("s_waitcnt vmcnt(0)" ::: "memory");   // h + prefetch + out drained
        __builtin_amdgcn_sched_barrier(0);
        __syncthreads();                                   // all waves drained
        if (tid == 0) {
            unsigned* fpw = flags + blk;
            unsigned val = (unsigned)(t + 2);
            asm volatile("global_store_dword %0, %1, off sc0 sc1" :: "v"(fpw), "v"(val) : "memory");
        }
    }
}

// =====================================================================
extern "C" void kernel_launch(void* const* d_in, const int* in_sizes, int n_in,
                              void* d_out, int out_size, void* d_ws, size_t ws_size,
                              hipStream_t stream) {
    const float* x    = (const float*)d_in[0];
    const float* W    = (const float*)d_in[1];
    const float* R    = (const float*)d_in[2];
    const float* bias = (const float*)d_in[3];
    float* out = (float*)d_out;

    char* ws = (char*)d_ws;
    size_t off = 0;
    u16* Af = (u16*)(ws + off); off += (size_t)16384 * 1024 * 2;  // 32MB
    u16* Bf = (u16*)(ws + off); off += (size_t)1024 * 4096 * 2;   // 8MB
    u16* Rp = (u16*)(ws + off); off += (size_t)1024 * 4096 * 2;   // 8MB
    u16* hbf = (u16*)(ws + off); off += (size_t)1 << 20;          // 1MB (2x64KB used)
    unsigned* flags = (unsigned*)(ws + off); off += 4096;         // 64 flags used
    size_t xp_need32 = (size_t)16384 * 4096 * 4;                  // 256MB
    int xp32 = (ws_size >= off + xp_need32) ? 1 : 0;
    float* xpf = (float*)(ws + off);
    u16*   xph = (u16*)(ws + off);

    pack_a<<<dim3(8192), dim3(256), 0, stream>>>(x, Af);
    pack_b<<<dim3(2048), dim3(256), 0, stream>>>(W, Bf);
    pack_r<<<dim3(2048), dim3(256), 0, stream>>>(R, Rp, flags);
    gemm1<<<dim3(4096), dim3(256), 0, stream>>>(Af, Bf, xpf, xph, xp32);

    void* args[] = { (void*)&xpf, (void*)&xph, (void*)&xp32, (void*)&Rp,
                     (void*)&bias, (void*)&hbf, (void*)&out, (void*)&flags };
    hipLaunchCooperativeKernel((const void*)scan_all, dim3(64), dim3(512), args, 0, stream);
}

// Round 3
// 2615.384 us; speedup vs baseline: 1.6486x; 1.6486x over previous
//
#include <hip/hip_runtime.h>

typedef unsigned short u16;
typedef short short8 __attribute__((ext_vector_type(8)));
typedef float f32x4 __attribute__((ext_vector_type(4)));
typedef unsigned int u32x4 __attribute__((ext_vector_type(4)));
typedef unsigned int u32x2 __attribute__((ext_vector_type(2)));
typedef unsigned short u16x4 __attribute__((ext_vector_type(4)));

#define Bsz 32
#define Tsz 512
#define Dsz 1024
#define Usz 1024
#define Gsz 4096   // 4*U

// ---- bf16 helpers (manual RNE) ----
static __device__ __forceinline__ u16 f2bf(float f) {
    unsigned int u = __float_as_uint(f);
    unsigned int lsb = (u >> 16) & 1u;
    u += 0x7fffu + lsb;
    return (u16)(u >> 16);
}
static __device__ __forceinline__ float bf2f(u16 b) {
    return __uint_as_float(((unsigned int)b) << 16);
}

// =====================================================================
// Pack kernels: MFMA-fragment-ordered bf16 buffers.
// A-frag (16x16x32): lane L holds A[m = mt*16 + (L&15)][k = kb*32 + (L>>4)*8 + j]
// B-frag:            lane L holds B[k = kb*32 + (L>>4)*8 + j][n = nt*16 + (L&15)]
// Flat: buf[((tile*32 + kb)*64 + L)*8 + j] -> lane-contiguous 16B chunks.
// =====================================================================

__global__ __launch_bounds__(256) void pack_a(const float* __restrict__ x, u16* __restrict__ Af) {
    size_t tid = (size_t)blockIdx.x * 256 + threadIdx.x;
    int L = (int)(tid & 63);
    size_t mtkb = tid >> 6;
    int kb = (int)(mtkb & 31);
    int mt = (int)(mtkb >> 5);
    int m  = mt * 16 + (L & 15);
    int d0 = kb * 32 + (L >> 4) * 8;
    const float* src = x + (size_t)m * Dsz + d0;
    short8 v;
#pragma unroll
    for (int j = 0; j < 8; ++j) v[j] = (short)f2bf(src[j]);
    *(short8*)(Af + tid * 8) = v;
}

__global__ __launch_bounds__(256) void pack_b(const float* __restrict__ W, u16* __restrict__ Bf) {
    size_t tid = (size_t)blockIdx.x * 256 + threadIdx.x;
    int L = (int)(tid & 63);
    size_t ntkb = tid >> 6;
    int kb = (int)(ntkb & 31);
    int nt = (int)(ntkb >> 5);
    int n  = nt * 16 + (L & 15);
    int k0 = kb * 32 + (L >> 4) * 8;
    short8 v;
#pragma unroll
    for (int j = 0; j < 8; ++j) v[j] = (short)f2bf(W[(size_t)(k0 + j) * Gsz + n]);
    *(short8*)(Bf + tid * 8) = v;
}

// R -> Rp gate-interleaved: tile=blk (0..255), col c=gate*4+du -> g=gate*1024+blk*4+du.
// Also zeroes the 512 barrier flags (two groups; ws is poisoned 0xAA before every call!).
__global__ __launch_bounds__(256) void pack_r(const float* __restrict__ R, u16* __restrict__ Rp,
                                              unsigned* __restrict__ flags) {
    if (blockIdx.x < 2) flags[blockIdx.x * 256 + threadIdx.x] = 0;
    size_t tid = (size_t)blockIdx.x * 256 + threadIdx.x;
    int L = (int)(tid & 63);
    size_t bkkb = tid >> 6;
    int kb  = (int)(bkkb & 31);
    int blk = (int)(bkkb >> 5);
    int c = L & 15;
    int gate = c >> 2, du = c & 3;
    int g = gate * 1024 + blk * 4 + du;
    int k0 = kb * 32 + (L >> 4) * 8;
    short8 v;
#pragma unroll
    for (int j = 0; j < 8; ++j) v[j] = (short)f2bf(R[(size_t)(k0 + j) * Gsz + g]);
    *(short8*)(Rp + tid * 8) = v;
}

// =====================================================================
// GEMM1: x_proj = X @ W; 128x128 tile, 4 waves. Epilogue writes the
// scan-friendly layout: [t][b][blk(256)][du(4)][gate(4)] so each scan
// gate-lane reads exactly one float4/u16x4 per (t,b).
// =====================================================================
__global__ __launch_bounds__(256) void gemm1(const u16* __restrict__ Af, const u16* __restrict__ Bf,
                                             float* __restrict__ xpf, u16* __restrict__ xph, int xp32) {
    __shared__ u16 smem[16 * 512];
    int bm = blockIdx.x >> 5;
    int bn = blockIdx.x & 31;
    int tid = threadIdx.x;
    int w = tid >> 6, ln = tid & 63;
    int mw = w & 1, nw = w >> 1;

    f32x4 acc[4][4];
#pragma unroll
    for (int i = 0; i < 4; ++i)
#pragma unroll
        for (int j = 0; j < 4; ++j) acc[i][j] = (f32x4){0.f, 0.f, 0.f, 0.f};

    for (int kb = 0; kb < 32; ++kb) {
        short8 tmp[4];
#pragma unroll
        for (int c2 = 0; c2 < 4; ++c2) {
            int chunk = w * 4 + c2;
            const u16* src = (chunk < 8)
                ? Af + (((size_t)(bm * 8 + chunk) * 32 + kb) * 64 + ln) * 8
                : Bf + (((size_t)(bn * 8 + (chunk - 8)) * 32 + kb) * 64 + ln) * 8;
            tmp[c2] = *(const short8*)src;
        }
#pragma unroll
        for (int c2 = 0; c2 < 4; ++c2) {
            int chunk = w * 4 + c2;
            *(short8*)(smem + chunk * 512 + ln * 8) = tmp[c2];
        }
        __syncthreads();
        short8 av[4], bv[4];
#pragma unroll
        for (int i = 0; i < 4; ++i) av[i] = *(const short8*)(smem + (mw * 4 + i) * 512 + ln * 8);
#pragma unroll
        for (int j = 0; j < 4; ++j) bv[j] = *(const short8*)(smem + (8 + nw * 4 + j) * 512 + ln * 8);
#pragma unroll
        for (int i = 0; i < 4; ++i)
#pragma unroll
            for (int j = 0; j < 4; ++j)
                acc[i][j] = __builtin_amdgcn_mfma_f32_16x16x32_bf16(av[i], bv[j], acc[i][j], 0, 0, 0);
        __syncthreads();
    }

    int quad = ln >> 4, c15 = ln & 15;
#pragma unroll
    for (int i = 0; i < 4; ++i) {
        int mt_g = bm * 8 + mw * 4 + i;
#pragma unroll
        for (int j = 0; j < 4; ++j) {
            int g = (bn * 8 + nw * 4 + j) * 16 + c15;
            int p = ((g & 1023) >> 2) * 16 + (g & 3) * 4 + (g >> 10);
#pragma unroll
            for (int r = 0; r < 4; ++r) {
                int row = mt_g * 16 + quad * 4 + r;
                int bb = row >> 9, tt = row & 511;
                size_t o = ((size_t)tt * Bsz + bb) * Gsz + p;
                if (xp32) xpf[o] = acc[i][j][r];
                else      xph[o] = f2bf(acc[i][j][r]);
            }
        }
    }
}

// =====================================================================
// Scan: 256 blocks x 384 threads (6 waves), TWO interleaved batch-group
// chains (G0 = batches 0..15, G1 = 16..31; M=16 = one native MFMA tile).
// Waves 0-3 = MFMA (K-slice w*256, both groups); wave4 = G0 gate wave;
// wave5 = G1 gate wave.  Per phase (G,t):
//   waves0-3: poll flags_G >= t+1 (all-wave poll; own flag included,
//             which bounds wave skew to 1 phase) -> bypass-load h_G
//             (8 x 16B/lane) -> MFMA (K=256) -> partial[G][w] -> barrier
//   gate wave G (after the SAME barrier): reduce partial[G][0..3] ->
//             proj -> gates -> bypass-store h_G -> vmcnt(0) ->
//             flag_G = t+2 -> issue x_proj prefetch for t+1
// Only ONE __syncthreads per phase.  G0's comm (flag store -> LLC ->
// other blocks' poll) hides under G1's phase and vice versa; the gate
// tail (transcendentals + store-ack + flag) is OFF the MFMA waves' path.
// partial[] is double-buffered by G: the poll ordering (flag set only
// AFTER the gate wave's partial read) makes re-write races impossible.
// proj is single-buffered: gate wave G reads it before it arrives at the
// next barrier, and gate wave G^1 writes only after that barrier.
// =====================================================================
__global__ __launch_bounds__(384) void scan_all(const float* __restrict__ xpf,
                                                const u16* __restrict__ xph, int xp32,
                                                const u16* __restrict__ Rp,
                                                const float* __restrict__ bias,
                                                u16* __restrict__ hbf, float* __restrict__ out,
                                                unsigned* __restrict__ flags) {
    __shared__ u16 lds_r[16384];          // 32KB: this block's Rp slice (16 cols x K=1024)
    __shared__ f32x4 partial[2][4][64];   // 8KB: [G][wave][lane]
    __shared__ float proj[16][17];        // 1.1KB

    int tid = threadIdx.x;
    int blk = blockIdx.x;
    int w = tid >> 6, ln = tid & 63, quad = ln >> 4, c15 = ln & 15;
    int bq = ln >> 2, du = ln & 3;        // gate-wave lane decomposition
    int u_g = blk * 4 + du;

    unsigned* flags0 = flags;             // group 0 flags[256]
    unsigned* flags1 = flags + 256;       // group 1 flags[256]

    u16* h00 = hbf;                       // G0 parity0 (written at even t)
    u16* h01 = hbf + 16384;               // G0 parity1 (written at odd t; zeros for t=0)
    u16* h10 = hbf + 32768;               // G1 parity0
    u16* h11 = hbf + 49152;               // G1 parity1

    // ---- stage Rp slice into LDS (fragment order preserved) ----
    if (tid < 256) {
#pragma unroll
        for (int i = 0; i < 8; ++i)
            *(short8*)(lds_r + tid * 64 + i * 8) = *(const short8*)(Rp + (size_t)blk * 16384 + tid * 64 + i * 8);
        // zero h_{-1} (parity-1 buffers, both groups) via bypass stores
        u32x4 z = (u32x4){0u, 0u, 0u, 0u};
#pragma unroll
        for (int i = 0; i < 8; ++i) {
            u16* p0 = h01 + tid * 64 + i * 8;
            u16* p1 = h11 + tid * 64 + i * 8;
            asm volatile("global_store_dwordx4 %0, %1, off sc0 sc1" :: "v"(p0), "v"(z) : "memory");
            asm volatile("global_store_dwordx4 %0, %1, off sc0 sc1" :: "v"(p1), "v"(z) : "memory");
        }
    }

    float bi0 = 0.f, bi1 = 0.f, bi2 = 0.f, bi3 = 0.f;
    float cs = 0.f, ns = 0.f, ms = 0.f;
    f32x4 xr4 = (f32x4){0.f, 0.f, 0.f, 0.f};
    u32x2 xr2 = (u32x2){0u, 0u};

    if (w >= 4) {                          // gate waves: bias + t=0 x_proj
        int G = w - 4;
        bi0 = bias[u_g]; bi1 = bias[1024 + u_g]; bi2 = bias[2048 + u_g]; bi3 = bias[3072 + u_g];
        size_t o0 = (size_t)(G * 16 + bq) * Gsz + blk * 16 + du * 4;   // t=0
        if (xp32) xr4 = *(const f32x4*)(xpf + o0);
        else      xr2 = *(const u32x2*)(xph + o0);
    }
    asm volatile("s_waitcnt vmcnt(0)" ::: "memory");
    __syncthreads();
    if (tid == 0) {
        unsigned one = 1;
        unsigned* f0 = flags0 + blk;
        unsigned* f1 = flags1 + blk;
        asm volatile("global_store_dword %0, %1, off sc0 sc1" :: "v"(f0), "v"(one) : "memory");
        asm volatile("global_store_dword %0, %1, off sc0 sc1" :: "v"(f1), "v"(one) : "memory");
    }

    auto phase = [&](int G, int t) {
        if (w < 4) {
            // ---- all-wave poll: 256 flags, 4/lane (own flag included) ----
            const unsigned* fp4 = (G ? flags1 : flags0) + ln * 4;
            unsigned tgt = (unsigned)(t + 1);
            u32x4 fv;
            do {
                asm volatile("global_load_dwordx4 %0, %1, off sc0 sc1\n\ts_waitcnt vmcnt(0)"
                             : "=v"(fv) : "v"(fp4) : "memory");
            } while (__any((int)(fv[0] < tgt || fv[1] < tgt || fv[2] < tgt || fv[3] < tgt)));

            // ---- bypass-load this wave's h_{t-1} fragment (8 x 16B/lane) ----
            const u16* hload = G ? ((t & 1) ? h10 : h11) : ((t & 1) ? h00 : h01);
            const u16* aBw = hload + (size_t)c15 * 1024 + w * 256 + quad * 8;
            short8 av[8];
#define LDH(i, OFF) asm volatile("global_load_dwordx4 %0, %1, off offset:" OFF " sc0 sc1" \
                                 : "=v"(av[i]) : "v"(aBw))
            LDH(0, "0");   LDH(1, "64");  LDH(2, "128"); LDH(3, "192");
            LDH(4, "256"); LDH(5, "320"); LDH(6, "384"); LDH(7, "448");
#undef LDH
            asm volatile("s_waitcnt vmcnt(0)" ::: "memory");
            __builtin_amdgcn_sched_barrier(0);

            // ---- MFMA: K=256 per wave, 2 independent chains ----
            f32x4 a0 = (f32x4){0.f, 0.f, 0.f, 0.f};
            f32x4 a1 = (f32x4){0.f, 0.f, 0.f, 0.f};
#pragma unroll
            for (int kk = 0; kk < 8; kk += 2) {
                short8 b0 = *(const short8*)(lds_r + ((w * 8 + kk) * 64 + ln) * 8);
                short8 b1 = *(const short8*)(lds_r + ((w * 8 + kk + 1) * 64 + ln) * 8);
                a0 = __builtin_amdgcn_mfma_f32_16x16x32_bf16(av[kk], b0, a0, 0, 0, 0);
                a1 = __builtin_amdgcn_mfma_f32_16x16x32_bf16(av[kk + 1], b1, a1, 0, 0, 0);
            }
            partial[G][w][ln] = a0 + a1;
        }
        __syncthreads();                   // the ONLY barrier this phase
        if (w == 4 + G) {
            // ---- reduce 4 K-slices, transpose via proj (within-wave) ----
            f32x4 s = partial[G][0][ln];
            s += partial[G][1][ln];
            s += partial[G][2][ln];
            s += partial[G][3][ln];
#pragma unroll
            for (int r = 0; r < 4; ++r) proj[quad * 4 + r][c15] = s[r];
            asm volatile("s_waitcnt lgkmcnt(0)" ::: "memory");
            __builtin_amdgcn_sched_barrier(0);

            // x_proj prefetch (issued last phase) is complete by now
            asm volatile("s_waitcnt vmcnt(0)" : "+v"(xr4), "+v"(xr2) :: "memory");
            __builtin_amdgcn_sched_barrier(0);
            float xv0, xv1, xv2, xv3;
            if (xp32) { xv0 = xr4[0]; xv1 = xr4[1]; xv2 = xr4[2]; xv3 = xr4[3]; }
            else {
                xv0 = bf2f((u16)(xr2[0] & 0xffffu)); xv1 = bf2f((u16)(xr2[0] >> 16));
                xv2 = bf2f((u16)(xr2[1] & 0xffffu)); xv3 = bf2f((u16)(xr2[1] >> 16));
            }

            float ip  = proj[bq][du]      + xv0 + bi0;
            float fp_ = proj[bq][4 + du]  + xv1 + bi1;
            float op_ = proj[bq][8 + du]  + xv2 + bi2;
            float zp  = proj[bq][12 + du] + xv3 + bi3;
            float sf = 1.f / (1.f + __expf(-fp_));
            float lf = __logf(sf + 1e-8f);
            float mn = fmaxf(ms + lf, ip);
            float it = __expf(ip - mn);
            float ft = __expf(ms + lf - mn);
            float ot = 1.f / (1.f + __expf(-op_));
            float zt = tanhf(zp);
            cs = ft * cs + it * zt;
            ns = ft * ns + it;
            ms = mn;
            float h = ot * (cs / (ns + 1e-8f));
            out[(size_t)(G * 16 + bq) * (Tsz * Usz) + (size_t)t * Usz + u_g] = h;  // plain (flushed at end)
            u16* hstore = G ? ((t & 1) ? h11 : h10) : ((t & 1) ? h01 : h00);
            u16* hp = hstore + bq * 1024 + u_g;
            unsigned hv = (unsigned)f2bf(h);
            asm volatile("global_store_short %0, %1, off sc0 sc1" :: "v"(hp), "v"(hv) : "memory");
            asm volatile("s_waitcnt vmcnt(0)" ::: "memory");   // h (+out) ack'd in LLC
            __builtin_amdgcn_sched_barrier(0);
            if (ln == 0) {
                unsigned* fm = (G ? flags1 : flags0) + blk;
                unsigned val = (unsigned)(t + 2);
                asm volatile("global_store_dword %0, %1, off sc0 sc1" :: "v"(fm), "v"(val) : "memory");
            }
            // issue x_proj prefetch for (G, t+1); drained before next gates
            int tn = (t + 1 < Tsz) ? t + 1 : t;
            size_t o = ((size_t)tn * Bsz + (G * 16 + bq)) * Gsz + blk * 16 + du * 4;
            if (xp32) {
                const float* p = xpf + o;
                asm volatile("global_load_dwordx4 %0, %1, off" : "=v"(xr4) : "v"(p));
            } else {
                const u16* p = xph + o;
                asm volatile("global_load_dwordx2 %0, %1, off" : "=v"(xr2) : "v"(p));
            }
        }
    };

    for (int t = 0; t < Tsz; ++t) {
        phase(0, t);
        phase(1, t);
    }
}

// =====================================================================
extern "C" void kernel_launch(void* const* d_in, const int* in_sizes, int n_in,
                              void* d_out, int out_size, void* d_ws, size_t ws_size,
                              hipStream_t stream) {
    const float* x    = (const float*)d_in[0];
    const float* W    = (const float*)d_in[1];
    const float* R    = (const float*)d_in[2];
    const float* bias = (const float*)d_in[3];
    float* out = (float*)d_out;

    char* ws = (char*)d_ws;
    size_t off = 0;
    u16* Af = (u16*)(ws + off); off += (size_t)16384 * 1024 * 2;  // 32MB
    u16* Bf = (u16*)(ws + off); off += (size_t)1024 * 4096 * 2;   // 8MB
    u16* Rp = (u16*)(ws + off); off += (size_t)1024 * 4096 * 2;   // 8MB
    u16* hbf = (u16*)(ws + off); off += (size_t)1 << 20;          // 1MB (4x32KB used)
    unsigned* flags = (unsigned*)(ws + off); off += 4096;         // 512 flags used
    size_t xp_need32 = (size_t)16384 * 4096 * 4;                  // 256MB
    int xp32 = (ws_size >= off + xp_need32) ? 1 : 0;
    float* xpf = (float*)(ws + off);
    u16*   xph = (u16*)(ws + off);

    pack_a<<<dim3(8192), dim3(256), 0, stream>>>(x, Af);
    pack_b<<<dim3(2048), dim3(256), 0, stream>>>(W, Bf);
    pack_r<<<dim3(2048), dim3(256), 0, stream>>>(R, Rp, flags);
    gemm1<<<dim3(4096), dim3(256), 0, stream>>>(Af, Bf, xpf, xph, xp32);

    void* args[] = { (void*)&xpf, (void*)&xph, (void*)&xp32, (void*)&Rp,
                     (void*)&bias, (void*)&hbf, (void*)&out, (void*)&flags };
    hipLaunchCooperativeKernel((const void*)scan_all, dim3(256), dim3(384), args, 0, stream);
}